// Round 6
// baseline (252.036 us; speedup 1.0000x reference)
//
#include <hip/hip_runtime.h>
#include <hip/hip_bf16.h>
#include <stdint.h>

typedef __bf16 bf16x8 __attribute__((ext_vector_type(8)));
typedef float f32x4 __attribute__((ext_vector_type(4)));
typedef unsigned short u16;
typedef u16 ushort4v __attribute__((ext_vector_type(4)));
typedef u16 ushort8v __attribute__((ext_vector_type(8)));

__device__ __forceinline__ u16 f2bf(float f) {
    union { float f; uint32_t u; } v; v.f = f;
    uint32_t u = v.u + 0x7FFFu + ((v.u >> 16) & 1u);
    return (u16)(u >> 16);
}
__device__ __forceinline__ float bf2f(u16 b) {
    union { uint32_t u; float f; } v; v.u = ((uint32_t)b) << 16;
    return v.f;
}
__device__ __forceinline__ float silu_f(float v) {
    return v / (1.0f + __expf(-v));
}
__device__ __forceinline__ void gload_lds16(const u16* g, u16* l) {
    __builtin_amdgcn_global_load_lds(
        (const __attribute__((address_space(1))) void*)g,
        (__attribute__((address_space(3))) void*)l, 16, 0, 0);
}

// ---------------- fused prep kernel (block-range dispatch) ----------------
__device__ __forceinline__ void trans_tile(
        const float* __restrict__ src, u16* __restrict__ dst, int R, int C,
        int bc, int br, float (*tt)[33], int tid) {
    const int tx = tid & 31, ty = tid >> 5;
#pragma unroll
    for (int i = 0; i < 4; i++)
        tt[ty + i * 8][tx] = src[(int64_t)(br * 32 + ty + i * 8) * C + bc * 32 + tx];
    __syncthreads();
#pragma unroll
    for (int i = 0; i < 4; i++)
        dst[(int64_t)(bc * 32 + ty + i * 8) * R + br * 32 + tx] = f2bf(tt[tx][ty + i * 8]);
}

__global__ __launch_bounds__(256) void prep_k(
        const float* __restrict__ x, u16* __restrict__ x_bf,
        const float* __restrict__ Wi, u16* __restrict__ Wti,
        const float* __restrict__ Wo, u16* __restrict__ Wto,
        const float* __restrict__ wx, u16* __restrict__ wxt) {
    __shared__ float tt[32][33];
    const int blk = blockIdx.x, tid = threadIdx.x;
    if (blk < 8192) {
        int i = blk * 256 + tid;
        float4 v = *(const float4*)&x[(int64_t)i * 4];
        ushort4v o = { f2bf(v.x), f2bf(v.y), f2bf(v.z), f2bf(v.w) };
        *(ushort4v*)&x_bf[(int64_t)i * 4] = o;
    } else if (blk < 12288) {
        int t = blk - 8192;        // W_in 1024x4096 -> Wt_in 4096x1024
        trans_tile(Wi, Wti, 1024, 4096, t & 127, t >> 7, tt, tid);
    } else if (blk < 14336) {
        int t = blk - 12288;       // W_out 2048x1024 -> Wt_out 1024x2048
        trans_tile(Wo, Wto, 2048, 1024, t & 31, t >> 5, tt, tid);
    } else {
        int idx = (blk - 14336) * 256 + tid;
        int j = idx >> 11, d = idx & 2047;
        wxt[idx] = (j < 33) ? f2bf(wx[d * 33 + j]) : (u16)0;
    }
}

// =======================================================================
// Deep-pipelined MFMA GEMM, C = A * Bt^T.
// Port-spread schedule: B-fragments are register double-buffered (bP/bQ)
// and prefetch-read for tile kt+1 during tile kt's middle phases, so no
// phase issues more than 8 ds_read_b128. B uses a 3-buffer LDS ring so
// B(kt+1) is vmcnt-drained + barrier-published BEFORE its prefetch reads.
// Per tile kt: reads q0:4A | q1:4A+4B' | q2:4A+4B' | q3:4A  (QPT=4)
//   stages    q0/q1: A(kt+1)->Abuf[(kt+1)&1] | q2/q3: B(kt+3)->Bbuf[(kt+3)%3]
//   tile-end vmcnt(4) leaves only B(kt+3) in flight (leads >= 2 phases).
// =======================================================================
template<int M_REP, int WARPS_M, int B_HALVES, bool OUT_BF16>
__global__ __launch_bounds__(512) void gemm_dp(
        const u16* __restrict__ A, const u16* __restrict__ Bt,
        void* __restrict__ Cout, int nbn_sh, int NT, int lda, int ldb, int ldc) {
    constexpr int WARPS_N = 8 / WARPS_M;
    constexpr int QPT = M_REP / 2;
    constexpr int WV_M = M_REP * 16;
    constexpr int BN = WARPS_N * 64;
    constexpr int B_T = BN * 64;              // u16 per B K-tile buffer
    constexpr int VKEEP = (B_HALVES == 2) ? 4 : 2;  // loads left in flight

    __shared__ __align__(16) u16 As[2 * 16384];   // 64 KB
    __shared__ __align__(16) u16 Bs[3 * B_T];     // 96 KB (G1) / 48 KB (G3)

    const int tid = threadIdx.x;
    const int wave = tid >> 6;
    const int lane = tid & 63;
    const int wm = wave / WARPS_N, wn = wave % WARPS_N;
    const int fr = lane & 15, fq = lane >> 4;

    // T1 bijective XCD swizzle (gridDim.x % 8 == 0 at both call sites)
    const int nwg = gridDim.x;
    const int cpx = nwg >> 3;
    const int swz = (blockIdx.x & 7) * cpx + (blockIdx.x >> 3);
    const int bm = swz >> nbn_sh;
    const int bn = swz & ((1 << nbn_sh) - 1);

    // stage side: linear LDS dest, inverse-swizzled global source (rule #21)
    const int srow = tid >> 3;
    const int scol8 = ((tid & 7) ^ (srow & 7)) * 8;
    const u16* gA = A + (int64_t)(bm * 256 + srow) * lda + scol8;
    const u16* gB = Bt + (int64_t)(bn * BN + srow) * ldb + scol8;
    const int64_t lda64 = lda, ldb64 = ldb;

    // read side (swizzled): u16 index = row*64 + ((kk*4+fq)^(fr&7))*8
    const int ksw0 = ((fq) ^ (fr & 7)) * 8;
    const int ksw1 = ((4 + fq) ^ (fr & 7)) * 8;
    const int arow0 = (wm * WV_M + fr) * 64;
    const int brow0 = (wn * 64 + fr) * 64;

    auto STAGE_A_HALF = [&](int kt, int h) {   // 2 loads -> Abuf[kt&1]
#pragma unroll
        for (int j = 0; j < 2; ++j)
            gload_lds16(gA + (int64_t)(h * 128 + j * 64) * lda64 + kt * 64,
                        &As[(kt & 1) * 16384 + h * 8192 + j * 4096 + tid * 8]);
    };
    auto STAGE_B_HALF = [&](int kt, int h) {   // 2 loads -> Bbuf[kt%3]
        const int bi = kt % 3;
#pragma unroll
        for (int j = 0; j < 2; ++j)
            gload_lds16(gB + (int64_t)(h * 128 + j * 64) * ldb64 + kt * 64,
                        &Bs[bi * B_T + h * 8192 + j * 4096 + tid * 8]);
    };
    auto ldA = [&](int kt, int m, int kk) -> bf16x8 {
        return *(const bf16x8*)&As[(kt & 1) * 16384 + arow0 + m * 1024 +
                                   (kk ? ksw1 : ksw0)];
    };
    auto ldB = [&](int kt, int n, int kk) -> bf16x8 {
        return *(const bf16x8*)&Bs[(kt % 3) * B_T + brow0 + n * 1024 +
                                   (kk ? ksw1 : ksw0)];
    };

    f32x4 acc[M_REP][4] = {};
    bf16x8 bP[4][2], bQ[4][2];

    // ---- prologue: A(0)->Abuf0; B(0..2)->Bbuf0..2; drain all but B(2) ----
    STAGE_A_HALF(0, 0); STAGE_A_HALF(0, 1);
#pragma unroll
    for (int h = 0; h < B_HALVES; ++h) STAGE_B_HALF(0, h);
#pragma unroll
    for (int h = 0; h < B_HALVES; ++h) STAGE_B_HALF(1, h);
#pragma unroll
    for (int h = 0; h < B_HALVES; ++h) STAGE_B_HALF(2, h);
    if constexpr (B_HALVES == 2) { asm volatile("s_waitcnt vmcnt(4)" ::: "memory"); }
    else                         { asm volatile("s_waitcnt vmcnt(2)" ::: "memory"); }
    __builtin_amdgcn_s_barrier();
#pragma unroll
    for (int n = 0; n < 4; ++n) { bP[n][0] = ldB(0, n, 0); bP[n][1] = ldB(0, n, 1); }

    auto runTile = [&](int kt, bf16x8 (&bu)[4][2], bf16x8 (&bf)[4][2]) {
        const bool pfB = (kt + 1 < NT);
        const bool stA = (kt + 1 < NT);
        const bool stB = (kt + 3 < NT);
#pragma unroll
        for (int q = 0; q < QPT; ++q) {
            // this phase's A fragments (current tile, published buffer)
            bf16x8 a00 = ldA(kt, 2 * q,     0), a01 = ldA(kt, 2 * q,     1);
            bf16x8 a10 = ldA(kt, 2 * q + 1, 0), a11 = ldA(kt, 2 * q + 1, 1);
            // B' prefetch reads for tile kt+1 (spread across middle phases)
            if constexpr (QPT == 4) {
                if (q == 1 && pfB) {
                    bf[0][0] = ldB(kt + 1, 0, 0); bf[0][1] = ldB(kt + 1, 0, 1);
                    bf[1][0] = ldB(kt + 1, 1, 0); bf[1][1] = ldB(kt + 1, 1, 1);
                }
                if (q == 2 && pfB) {
                    bf[2][0] = ldB(kt + 1, 2, 0); bf[2][1] = ldB(kt + 1, 2, 1);
                    bf[3][0] = ldB(kt + 1, 3, 0); bf[3][1] = ldB(kt + 1, 3, 1);
                }
            } else {
                if (q == 0 && pfB) {
                    bf[0][0] = ldB(kt + 1, 0, 0); bf[0][1] = ldB(kt + 1, 0, 1);
                    bf[1][0] = ldB(kt + 1, 1, 0); bf[1][1] = ldB(kt + 1, 1, 1);
                }
                if (q == 1 && pfB) {
                    bf[2][0] = ldB(kt + 1, 2, 0); bf[2][1] = ldB(kt + 1, 2, 1);
                    bf[3][0] = ldB(kt + 1, 3, 0); bf[3][1] = ldB(kt + 1, 3, 1);
                }
            }
            // staging (2-4 global_load_lds per phase)
            if constexpr (QPT == 4) {
                if (q == 0 && stA) STAGE_A_HALF(kt + 1, 0);
                if (q == 1 && stA) STAGE_A_HALF(kt + 1, 1);
                if (q == 2 && stB) STAGE_B_HALF(kt + 3, 0);
                if (q == 3 && stB) STAGE_B_HALF(kt + 3, 1);
            } else {
                if (q == 0 && stA) { STAGE_A_HALF(kt + 1, 0); STAGE_A_HALF(kt + 1, 1); }
                if (q == 1 && stB) { STAGE_B_HALF(kt + 3, 0); }
            }
            __builtin_amdgcn_s_barrier();
            __builtin_amdgcn_s_setprio(1);
#pragma unroll
            for (int n = 0; n < 4; ++n) {
                acc[2 * q][n]     = __builtin_amdgcn_mfma_f32_16x16x32_bf16(a00, bu[n][0], acc[2 * q][n], 0, 0, 0);
                acc[2 * q][n]     = __builtin_amdgcn_mfma_f32_16x16x32_bf16(a01, bu[n][1], acc[2 * q][n], 0, 0, 0);
                acc[2 * q + 1][n] = __builtin_amdgcn_mfma_f32_16x16x32_bf16(a10, bu[n][0], acc[2 * q + 1][n], 0, 0, 0);
                acc[2 * q + 1][n] = __builtin_amdgcn_mfma_f32_16x16x32_bf16(a11, bu[n][1], acc[2 * q + 1][n], 0, 0, 0);
            }
            __builtin_amdgcn_s_setprio(0);
            if (q == QPT - 1) {   // counted wait only at K-tile end; never 0 mid-loop
                if (kt + 3 < NT) {
                    if constexpr (B_HALVES == 2) { asm volatile("s_waitcnt vmcnt(4)" ::: "memory"); }
                    else                         { asm volatile("s_waitcnt vmcnt(2)" ::: "memory"); }
                } else {
                    asm volatile("s_waitcnt vmcnt(0)" ::: "memory");
                }
            }
            __builtin_amdgcn_s_barrier();
        }
    };

    for (int tp = 0; tp < NT; tp += 2) {
        runTile(tp,     bP, bQ);
        runTile(tp + 1, bQ, bP);
    }

    // ---- epilogue ----
#pragma unroll
    for (int m = 0; m < M_REP; ++m) {
#pragma unroll
        for (int n = 0; n < 4; ++n) {
            const int col = bn * BN + wn * 64 + n * 16 + fr;
#pragma unroll
            for (int r = 0; r < 4; ++r) {
                const int row = bm * 256 + wm * WV_M + m * 16 + fq * 4 + r;
                if constexpr (OUT_BF16)
                    ((u16*)Cout)[(int64_t)row * ldc + col] = f2bf(acc[m][n][r]);
                else
                    ((float*)Cout)[(int64_t)row * ldc + col] = acc[m][n][r];
            }
        }
    }
}

// ---------------- depthwise conv(4) + bias + SiLU ----------------
__global__ __launch_bounds__(256) void conv_silu_k(
        const u16* __restrict__ xz, const float* __restrict__ cw,
        const float* __restrict__ cb, u16* __restrict__ xc) {
    const int blk = blockIdx.x;
    const int b = blk >> 9;
    const int l0 = (blk & 511) << 2;
    const int d0 = threadIdx.x * 8;
    float w[8][4], bias[8];
#pragma unroll
    for (int j = 0; j < 8; j++) {
        float4 wv = *(const float4*)&cw[(d0 + j) * 4];
        w[j][0] = wv.x; w[j][1] = wv.y; w[j][2] = wv.z; w[j][3] = wv.w;
        bias[j] = cb[d0 + j];
    }
    float xp[7][8];
#pragma unroll
    for (int r = 0; r < 7; r++) {
        int l = l0 - 3 + r;
        if (l < 0) {
#pragma unroll
            for (int j = 0; j < 8; j++) xp[r][j] = 0.f;
        } else {
            ushort8v v = *(const ushort8v*)&xz[((int64_t)(b * 2048 + l)) * 4096 + d0];
#pragma unroll
            for (int j = 0; j < 8; j++) xp[r][j] = bf2f(v[j]);
        }
    }
#pragma unroll
    for (int li = 0; li < 4; li++) {
        ushort8v o;
#pragma unroll
        for (int j = 0; j < 8; j++) {
            float s = bias[j];
#pragma unroll
            for (int k = 0; k < 4; k++) s += w[j][k] * xp[li + k][j];
            o[j] = f2bf(silu_f(s));
        }
        *(ushort8v*)&xc[((int64_t)(b * 2048 + l0 + li)) * 2048 + d0] = o;
    }
}

// ---------------- ssm projection (K split by 4), spart: [4][8192][48] ----------------
__global__ __launch_bounds__(256) void ssm_proj_k(
        const u16* __restrict__ xc, const u16* __restrict__ wxt,
        float* __restrict__ spart) {
    const int gw = (blockIdx.x << 2) + (threadIdx.x >> 6);
    const int lane = threadIdx.x & 63;
    const int rb = gw >> 2, kc = gw & 3;
    const int fr = lane & 15, fq = lane >> 4;
    const u16* ap = xc + (int64_t)(rb * 16 + fr) * 2048 + kc * 512 + fq * 8;
    const u16* bp = wxt + (int64_t)fr * 2048 + kc * 512 + fq * 8;
    f32x4 acc0 = {}, acc1 = {}, acc2 = {};
#pragma unroll 4
    for (int k = 0; k < 512; k += 32) {
        bf16x8 av = *(const bf16x8*)(ap + k);
        bf16x8 b0 = *(const bf16x8*)(bp + k);
        bf16x8 b1 = *(const bf16x8*)(bp + 16 * 2048 + k);
        bf16x8 b2 = *(const bf16x8*)(bp + 32 * 2048 + k);
        acc0 = __builtin_amdgcn_mfma_f32_16x16x32_bf16(av, b0, acc0, 0, 0, 0);
        acc1 = __builtin_amdgcn_mfma_f32_16x16x32_bf16(av, b1, acc1, 0, 0, 0);
        acc2 = __builtin_amdgcn_mfma_f32_16x16x32_bf16(av, b2, acc2, 0, 0, 0);
    }
    float* sp = spart + ((int64_t)kc * 8192 + rb * 16) * 48;
#pragma unroll
    for (int r = 0; r < 4; r++) {
        int ro = (fq * 4 + r) * 48;
        sp[ro + fr] = acc0[r];
        sp[ro + 16 + fr] = acc1[r];
        sp[ro + 32 + fr] = acc2[r];
    }
}

__global__ __launch_bounds__(256) void ssm_fin_k(
        const float* __restrict__ spart, float* __restrict__ dB,
        float* __restrict__ Cm) {
    const int row = blockIdx.x * 256 + threadIdx.x;
    const float* sp = spart + (int64_t)row * 48;
    float s[33];
#pragma unroll
    for (int j = 0; j < 33; j++)
        s[j] = sp[j] + sp[8192 * 48 + j] + sp[2 * 8192 * 48 + j] + sp[3 * 8192 * 48 + j];
    float d0v = s[0];
    float delta = (d0v > 20.f) ? d0v : log1pf(__expf(d0v));
#pragma unroll
    for (int n = 0; n < 16; n++) {
        dB[(int64_t)row * 16 + n] = delta * s[1 + n] * (1.0f / 2048.0f);
        Cm[(int64_t)row * 16 + n] = s[17 + n];
    }
}

__global__ __launch_bounds__(256) void h_part_k(
        const u16* __restrict__ xc, const float* __restrict__ dB,
        float* __restrict__ hp) {
    const int blk = blockIdx.x;
    const int dt = blk & 7, b = (blk >> 3) & 3, lc = blk >> 5;
    const int d = dt * 256 + threadIdx.x;
    const u16* xp = xc + ((int64_t)(b * 2048 + lc * 256)) * 2048 + d;
    const float* dbp = dB + (int64_t)(b * 2048 + lc * 256) * 16;
    float acc[16] = {};
    for (int l = 0; l < 256; l++) {
        float xv = bf2f(xp[(int64_t)l * 2048]);
#pragma unroll
        for (int n = 0; n < 16; n++) acc[n] += xv * dbp[l * 16 + n];
    }
    float* o = hp + ((int64_t)((lc * 4 + b) * 2048 + d)) * 16;
#pragma unroll
    for (int n = 0; n < 16; n++) o[n] = acc[n];
}

__global__ void h_red_k(const float* __restrict__ hp, float* __restrict__ h) {
    const int i = blockIdx.x * 256 + threadIdx.x;  // < 131072
    float s = 0.f;
#pragma unroll
    for (int c = 0; c < 8; c++) s += hp[(int64_t)c * 131072 + i];
    h[i] = s;
}

__global__ __launch_bounds__(256) void y_gate_k(
        u16* __restrict__ xz, const u16* __restrict__ xc,
        const float* __restrict__ h, const float* __restrict__ Cm,
        const float* __restrict__ Dp) {
    const int blk = blockIdx.x;
    const int lc = blk & 63, dt = (blk >> 6) & 1, b = blk >> 7;
    const int d0 = dt * 1024 + threadIdx.x * 4;
    const float* hpp = h + ((int64_t)(b * 2048 + d0)) * 16;
    float hreg[4][16];
#pragma unroll
    for (int i = 0; i < 4; i++)
#pragma unroll
        for (int n = 0; n < 16; n++) hreg[i][n] = hpp[i * 16 + n];
    float Dv[4];
#pragma unroll
    for (int i = 0; i < 4; i++) Dv[i] = Dp[d0 + i];
    __shared__ float Cs[32][16];
    if (threadIdx.x < 128)
        ((float4*)&Cs[0][0])[threadIdx.x] =
            ((const float4*)(Cm + (int64_t)(b * 2048 + lc * 32) * 16))[threadIdx.x];
    __syncthreads();
    for (int li = 0; li < 32; li++) {
        const int64_t rowz = (int64_t)(b * 2048 + lc * 32 + li);
        ushort4v xcv = *(const ushort4v*)&xc[rowz * 2048 + d0];
        ushort4v zv = *(const ushort4v*)&xz[rowz * 4096 + 2048 + d0];
        ushort4v o;
#pragma unroll
        for (int i = 0; i < 4; i++) {
            float s = Dv[i] * bf2f(xcv[i]);
#pragma unroll
            for (int n = 0; n < 16; n++) s += hreg[i][n] * Cs[li][n];
            o[i] = f2bf(s * silu_f(bf2f(zv[i])));
        }
        *(ushort4v*)&xz[rowz * 4096 + d0] = o;
    }
}

extern "C" void kernel_launch(void* const* d_in, const int* in_sizes, int n_in,
                              void* d_out, int out_size, void* d_ws, size_t ws_size,
                              hipStream_t stream) {
    (void)in_sizes; (void)n_in; (void)out_size; (void)ws_size;
    const float* x      = (const float*)d_in[0];
    const float* W_in   = (const float*)d_in[1];
    const float* conv_w = (const float*)d_in[2];
    const float* conv_b = (const float*)d_in[3];
    const float* W_xp   = (const float*)d_in[4];
    const float* Dp     = (const float*)d_in[6];   // d_in[5] = A_log, unused by reference
    const float* W_out  = (const float*)d_in[7];
    float* out = (float*)d_out;
    char* ws = (char*)d_ws;

    u16*   x_bf   = (u16*)(ws);                   // 16,777,216 B (dead after GEMM1)
    float* spart  = (float*)(ws);                 // alias: 6,291,456
    float* dB     = (float*)(ws + 6291456);       // 524,288
    float* Cm     = (float*)(ws + 6815744);       // 524,288
    float* hp     = (float*)(ws + 7340032);       // 4,194,304
    float* h      = (float*)(ws + 11534336);      // 524,288
    u16*   Wt_in  = (u16*)(ws + 16777216);        // 8,388,608
    u16*   Wt_out = (u16*)(ws + 25165824);        // 4,194,304
    u16*   Wxt    = (u16*)(ws + 29360128);        // 196,608
    u16*   xz     = (u16*)(ws + 29556736);        // 67,108,864
    u16*   xcv    = (u16*)(ws + 96665600);        // 33,554,432  (total ~130 MB)

    prep_k<<<14720, 256, 0, stream>>>(x, x_bf, W_in, Wt_in, W_out, Wt_out, W_xp, Wxt);
    // xz = x @ W_in : M=8192 N=4096 K=1024; grid (8192/256)*(4096/256)=512
    gemm_dp<8, 2, 2, true><<<512, 512, 0, stream>>>(x_bf, Wt_in, xz, 4, 16, 1024, 1024, 4096);
    conv_silu_k<<<2048, 256, 0, stream>>>(xz, conv_w, conv_b, xcv);
    ssm_proj_k<<<512, 256, 0, stream>>>(xcv, Wxt, spart);
    ssm_fin_k<<<32, 256, 0, stream>>>(spart, dB, Cm);
    h_part_k<<<256, 256, 0, stream>>>(xcv, dB, hp);
    h_red_k<<<512, 256, 0, stream>>>(hp, h);
    y_gate_k<<<512, 256, 0, stream>>>(xz, xcv, h, Cm, Dp);
    // out = y @ W_out : M=8192 N=1024 K=2048; grid (8192/256)*(1024/128)=256
    gemm_dp<4, 4, 1, false><<<256, 512, 0, stream>>>(xz, Wt_out, out, 3, 32, 4096, 2048, 1024);
}